// Round 2
// baseline (837.074 us; speedup 1.0000x reference)
//
#include <hip/hip_runtime.h>
#include <math.h>

#define KTOP 5
#define EC   27    // edge candidate classes
#define RPB  256   // edge rows per block (one per thread)

typedef float floatx4 __attribute__((ext_vector_type(4)));  // native vec for nontemporal store

// ---------------- node-path helpers (unchanged, harness-verified) -------------

// Tree argmax over the low WIDTH lanes of the wave (result broadcast to all 64).
// Tie-break: smaller index wins (matches jax.lax.top_k).
template <int WIDTH>
__device__ __forceinline__ void wave_argmax(float& v, int& i) {
#pragma unroll
    for (int off = WIDTH / 2; off > 0; off >>= 1) {
        float ov = __shfl_down(v, off);
        int   oi = __shfl_down(i, off);
        bool take = (ov > v) || (ov == v && oi < i);
        v = take ? ov : v;
        i = take ? oi : i;
    }
    v = __shfl(v, 0);
    i = __shfl(i, 0);
}

// Each lane owns 8 consecutive output columns: col = lane*8.
__device__ __forceinline__ void gather_store(const float* __restrict__ table,
                                             const int* sel,
                                             float* __restrict__ outrow,
                                             int lane) {
    const int col = lane * 8;
    float acc[8] = {0.f, 0.f, 0.f, 0.f, 0.f, 0.f, 0.f, 0.f};
#pragma unroll
    for (int k = 0; k < KTOP; ++k) {
        const float4* t = reinterpret_cast<const float4*>(table + (size_t)sel[k] * 512 + col);
        float4 a = t[0];
        float4 b = t[1];
        acc[0] += a.x; acc[1] += a.y; acc[2] += a.z; acc[3] += a.w;
        acc[4] += b.x; acc[5] += b.y; acc[6] += b.z; acc[7] += b.w;
    }
    float4* o = reinterpret_cast<float4*>(outrow + col);
    o[0] = make_float4(acc[0], acc[1], acc[2], acc[3]);
    o[1] = make_float4(acc[4], acc[5], acc[6], acc[7]);
}

// ------------------------------------------------------------------------------

__global__ __launch_bounds__(256) void select_topk_kernel(
    const float* __restrict__ node_w,   // [N,160]
    const float* __restrict__ edge_w,   // [E,27]
    const float* __restrict__ knode_t,  // [160,512]
    const float* __restrict__ kedge_t,  // [27,512]
    float* __restrict__ out_node,       // [N,512]
    float* __restrict__ out_edge,       // [E,512]
    int N, int E, int node_blocks) {
    __shared__ float wbuf[RPB * EC];    // 27648 B: 256 edge rows staged per block

    const int tid  = threadIdx.x;
    const int wave = tid >> 6;
    const int lane = tid & 63;

    if ((int)blockIdx.x < node_blocks) {
        // ---- node rows: 160 candidate classes per row (wave-per-row; 600 rows,
        //      negligible total cost — kept identical to verified baseline) ----
        const int row = blockIdx.x * 4 + wave;
        if (row >= N) return;
        const float* w = node_w + (size_t)row * 160;
        float v0 = w[lane];
        float v1 = w[64 + lane];
        float v2 = (lane < 32) ? w[128 + lane] : -INFINITY;
        int sel[KTOP];
#pragma unroll
        for (int k = 0; k < KTOP; ++k) {
            float lv = v0; int li = lane;
            if (v1 > lv) { lv = v1; li = lane + 64; }
            if (v2 > lv) { lv = v2; li = lane + 128; }
            wave_argmax<64>(lv, li);
            sel[k] = li;
            if (li == lane)            v0 = -INFINITY;
            else if (li == lane + 64)  v1 = -INFINITY;
            else if (li == lane + 128) v2 = -INFINITY;
        }
        gather_store(knode_t, sel, out_node + (size_t)row * 512, lane);
        return;
    }

    // ---- edge rows: 27 candidates, ONE LANE PER ROW ----
    const int first_row = ((int)blockIdx.x - node_blocks) * RPB;
    const int total_elems = E * EC;           // 9.7M, fits int
    const int base = first_row * EC;

    // Stage 256 rows (6912 dwords) into LDS, perfectly coalesced.
#pragma unroll
    for (int i = 0; i < EC; ++i) {
        int g = base + i * RPB + tid;
        float val = 0.f;
        if (g < total_elems) val = edge_w[g];
        wbuf[i * RPB + tid] = val;
    }
    __syncthreads();

    // Each thread owns row (first_row + tid). Read its 27 values from LDS
    // (stride 27 dwords: gcd(27,32)=1 -> conflict-free) as monotonic u32 keys.
    unsigned key[EC];
#pragma unroll
    for (int j = 0; j < EC; ++j) {
        unsigned u = __float_as_uint(wbuf[tid * EC + j]);
        key[j] = ((int)u < 0) ? ~u : (u | 0x80000000u);
    }

    // Top-5 of 27 in registers. Strict '>' forward scan => smallest index wins
    // ties (matches jax.lax.top_k). Selected key masked to 0 (= -NaN, below any
    // real input). All indices compile-time via full unroll -> no scratch.
    unsigned packed = 0;
#pragma unroll
    for (int k = 0; k < KTOP; ++k) {
        unsigned best = key[0];
        int bsel = 0;
#pragma unroll
        for (int j = 1; j < EC; ++j) {
            bool t = key[j] > best;
            best = t ? key[j] : best;
            bsel = t ? j : bsel;
        }
        packed |= (unsigned)bsel << (5 * k);
#pragma unroll
        for (int j = 0; j < EC; ++j)
            key[j] = (j == bsel) ? 0u : key[j];
    }

    // Gather + store: wave walks its 64 rows; per row one v_readlane (SGPR
    // result -> scalar table addressing), 10 coalesced float4 loads from the
    // L2-resident 55KB table, 2 nontemporal float4 stores (2KB/wave, coalesced).
    const int wrow0 = first_row + wave * 64;
    const int nrows = min(64, E - wrow0);     // may be <=0 in tail block
    const int col = lane * 8;
    for (int r = 0; r < nrows; ++r) {
        unsigned pk = (unsigned)__builtin_amdgcn_readlane((int)packed, r);
        float acc[8] = {0.f, 0.f, 0.f, 0.f, 0.f, 0.f, 0.f, 0.f};
#pragma unroll
        for (int k = 0; k < KTOP; ++k) {
            int idx = (int)((pk >> (5 * k)) & 31u);
            const float4* t = reinterpret_cast<const float4*>(kedge_t + (size_t)idx * 512 + col);
            float4 a = t[0];
            float4 b = t[1];
            acc[0] += a.x; acc[1] += a.y; acc[2] += a.z; acc[3] += a.w;
            acc[4] += b.x; acc[5] += b.y; acc[6] += b.z; acc[7] += b.w;
        }
        float* orow = out_edge + (size_t)(wrow0 + r) * 512 + col;
        floatx4 o0 = {acc[0], acc[1], acc[2], acc[3]};
        floatx4 o1 = {acc[4], acc[5], acc[6], acc[7]};
        floatx4* op = reinterpret_cast<floatx4*>(orow);
        __builtin_nontemporal_store(o0, op);
        __builtin_nontemporal_store(o1, op + 1);
    }
}

extern "C" void kernel_launch(void* const* d_in, const int* in_sizes, int n_in,
                              void* d_out, int out_size, void* d_ws, size_t ws_size,
                              hipStream_t stream) {
    const float* node_w  = (const float*)d_in[0];
    const float* edge_w  = (const float*)d_in[1];
    const float* knode_t = (const float*)d_in[2];
    const float* kedge_t = (const float*)d_in[3];

    const int N = in_sizes[0] / 160;  // 600
    const int E = in_sizes[1] / 27;   // 359400

    float* out      = (float*)d_out;
    float* out_node = out;
    float* out_edge = out + (size_t)N * 512;

    const int node_blocks = (N + 3) / 4;            // 4 node rows (waves) per block
    const int edge_blocks = (E + RPB - 1) / RPB;    // 256 edge rows per block

    dim3 grid(node_blocks + edge_blocks);
    dim3 block(256);
    hipLaunchKernelGGL(select_topk_kernel, grid, block, 0, stream,
                       node_w, edge_w, knode_t, kedge_t,
                       out_node, out_edge, N, E, node_blocks);
}

// Round 3
// 779.560 us; speedup vs baseline: 1.0738x; 1.0738x over previous
//
#include <hip/hip_runtime.h>
#include <math.h>

#define KTOP 5
#define EC   27            // edge candidate classes
#define RPB  256           // edge rows per block (one per thread)
#define TBL_FLOATS (EC * 512)   // 13824 floats = 55296 B

typedef float floatx4 __attribute__((ext_vector_type(4)));

// ---------------- node-path helpers (unchanged, harness-verified) -------------

// Tree argmax over the low WIDTH lanes of the wave (result broadcast to all 64).
// Tie-break: smaller index wins (matches jax.lax.top_k).
template <int WIDTH>
__device__ __forceinline__ void wave_argmax(float& v, int& i) {
#pragma unroll
    for (int off = WIDTH / 2; off > 0; off >>= 1) {
        float ov = __shfl_down(v, off);
        int   oi = __shfl_down(i, off);
        bool take = (ov > v) || (ov == v && oi < i);
        v = take ? ov : v;
        i = take ? oi : i;
    }
    v = __shfl(v, 0);
    i = __shfl(i, 0);
}

// Each lane owns 8 consecutive output columns: col = lane*8 (node path only).
__device__ __forceinline__ void gather_store(const float* __restrict__ table,
                                             const int* sel,
                                             float* __restrict__ outrow,
                                             int lane) {
    const int col = lane * 8;
    float acc[8] = {0.f, 0.f, 0.f, 0.f, 0.f, 0.f, 0.f, 0.f};
#pragma unroll
    for (int k = 0; k < KTOP; ++k) {
        const float4* t = reinterpret_cast<const float4*>(table + (size_t)sel[k] * 512 + col);
        float4 a = t[0];
        float4 b = t[1];
        acc[0] += a.x; acc[1] += a.y; acc[2] += a.z; acc[3] += a.w;
        acc[4] += b.x; acc[5] += b.y; acc[6] += b.z; acc[7] += b.w;
    }
    float4* o = reinterpret_cast<float4*>(outrow + col);
    o[0] = make_float4(acc[0], acc[1], acc[2], acc[3]);
    o[1] = make_float4(acc[4], acc[5], acc[6], acc[7]);
}

// ------------------------------------------------------------------------------

__global__ __launch_bounds__(256) void select_topk_kernel(
    const float* __restrict__ node_w,   // [N,160]
    const float* __restrict__ edge_w,   // [E,27]
    const float* __restrict__ knode_t,  // [160,512]
    const float* __restrict__ kedge_t,  // [27,512]
    float* __restrict__ out_node,       // [N,512]
    float* __restrict__ out_edge,       // [E,512]
    int N, int E, int node_blocks) {
    // Shared buffer, time-shared:
    //   phase 1: first RPB*EC floats = staged edge-weight rows (wbuf)
    //   phase 2: full TBL_FLOATS     = the 27x512 kedge table
    __shared__ float smem[TBL_FLOATS];  // 55296 B -> 2 blocks/CU

    const int tid  = threadIdx.x;
    const int wave = tid >> 6;
    const int lane = tid & 63;

    if ((int)blockIdx.x < node_blocks) {
        // ---- node rows: 160 candidates, wave-per-row (600 rows, negligible) ----
        const int row = blockIdx.x * 4 + wave;
        if (row >= N) return;
        const float* w = node_w + (size_t)row * 160;
        float v0 = w[lane];
        float v1 = w[64 + lane];
        float v2 = (lane < 32) ? w[128 + lane] : -INFINITY;
        int sel[KTOP];
#pragma unroll
        for (int k = 0; k < KTOP; ++k) {
            float lv = v0; int li = lane;
            if (v1 > lv) { lv = v1; li = lane + 64; }
            if (v2 > lv) { lv = v2; li = lane + 128; }
            wave_argmax<64>(lv, li);
            sel[k] = li;
            if (li == lane)            v0 = -INFINITY;
            else if (li == lane + 64)  v1 = -INFINITY;
            else if (li == lane + 128) v2 = -INFINITY;
        }
        gather_store(knode_t, sel, out_node + (size_t)row * 512, lane);
        return;
    }

    // ---- edge rows: 27 candidates, ONE LANE PER ROW, table gathered from LDS ----
    const int first_row = ((int)blockIdx.x - node_blocks) * RPB;
    const int total_elems = E * EC;           // 9.7M, fits int
    const int base = first_row * EC;

    // Phase 1: stage 256 rows (6912 dwords) into LDS, fully coalesced linear copy.
#pragma unroll
    for (int i = 0; i < EC; ++i) {
        int g = base + i * RPB + tid;
        float val = 0.f;
        if (g < total_elems) val = edge_w[g];
        smem[i * RPB + tid] = val;
    }
    __syncthreads();

    // Each thread owns row (first_row + tid): read its 27 values from LDS
    // (stride 27 dwords, gcd(27,32)=1 -> conflict-free) as monotonic u32 keys.
    unsigned key[EC];
#pragma unroll
    for (int j = 0; j < EC; ++j) {
        unsigned u = __float_as_uint(smem[tid * EC + j]);
        key[j] = ((int)u < 0) ? ~u : (u | 0x80000000u);
    }
    __syncthreads();   // all wbuf reads done before the table overwrites smem

    // Phase 2: stage the whole 27x512 table into LDS (coalesced dwordx4).
    {
        const floatx4* src = reinterpret_cast<const floatx4*>(kedge_t);
        floatx4* dst = reinterpret_cast<floatx4*>(smem);
        for (int i = tid; i < TBL_FLOATS / 4; i += RPB)
            dst[i] = src[i];
    }

    // Top-5 of 27 in registers (overlaps with table loads in flight).
    // Strict '>' forward scan => smallest index wins ties (jax.lax.top_k).
    // Selected key masked to 0. Fully unrolled -> all-VGPR.
    unsigned packed = 0;
#pragma unroll
    for (int k = 0; k < KTOP; ++k) {
        unsigned best = key[0];
        int bsel = 0;
#pragma unroll
        for (int j = 1; j < EC; ++j) {
            bool t = key[j] > best;
            best = t ? key[j] : best;
            bsel = t ? j : bsel;
        }
        packed |= (unsigned)bsel << (5 * k);
#pragma unroll
        for (int j = 0; j < EC; ++j)
            key[j] = (j == bsel) ? 0u : key[j];
    }
    __syncthreads();   // table fully staged

    // Gather + store: wave walks its 64 rows. Per row: one v_readlane (scalar
    // selector), 10 conflict-free ds_read_b128 (lane stride 16B), 2 coalesced
    // nontemporal float4 stores. Lane l owns cols [4l,4l+4) and [256+4l,...).
    const int wrow0 = first_row + wave * 64;
    const int nrows = min(64, E - wrow0);     // may be <=0 in tail block
    const int c_lo = lane * 4;
    const int c_hi = 256 + lane * 4;
#pragma unroll 2
    for (int r = 0; r < nrows; ++r) {
        unsigned pk = (unsigned)__builtin_amdgcn_readlane((int)packed, r);
        floatx4 acc_lo = {0.f, 0.f, 0.f, 0.f};
        floatx4 acc_hi = {0.f, 0.f, 0.f, 0.f};
#pragma unroll
        for (int k = 0; k < KTOP; ++k) {
            int idx = (int)((pk >> (5 * k)) & 31u);
            const float* trow = smem + idx * 512;
            floatx4 tlo = *reinterpret_cast<const floatx4*>(trow + c_lo);
            floatx4 thi = *reinterpret_cast<const floatx4*>(trow + c_hi);
            acc_lo += tlo;
            acc_hi += thi;
        }
        float* orow = out_edge + (size_t)(wrow0 + r) * 512;
        __builtin_nontemporal_store(acc_lo, reinterpret_cast<floatx4*>(orow + c_lo));
        __builtin_nontemporal_store(acc_hi, reinterpret_cast<floatx4*>(orow + c_hi));
    }
}

extern "C" void kernel_launch(void* const* d_in, const int* in_sizes, int n_in,
                              void* d_out, int out_size, void* d_ws, size_t ws_size,
                              hipStream_t stream) {
    const float* node_w  = (const float*)d_in[0];
    const float* edge_w  = (const float*)d_in[1];
    const float* knode_t = (const float*)d_in[2];
    const float* kedge_t = (const float*)d_in[3];

    const int N = in_sizes[0] / 160;  // 600
    const int E = in_sizes[1] / 27;   // 359400

    float* out      = (float*)d_out;
    float* out_node = out;
    float* out_edge = out + (size_t)N * 512;

    const int node_blocks = (N + 3) / 4;            // 4 node rows (waves) per block
    const int edge_blocks = (E + RPB - 1) / RPB;    // 256 edge rows per block

    dim3 grid(node_blocks + edge_blocks);
    dim3 block(256);
    hipLaunchKernelGGL(select_topk_kernel, grid, block, 0, stream,
                       node_w, edge_w, knode_t, kedge_t,
                       out_node, out_edge, N, E, node_blocks);
}